// Round 1
// baseline (7212.202 us; speedup 1.0000x reference)
//
#include <hip/hip_runtime.h>
#include <math.h>

#define HD 128   // HIDDEN_DIM
#define KD 256   // INPUT_DIM

// ---------------- degree count (per-relation, src and dst) ----------------
__global__ void deg_kernel(const int* __restrict__ cps, const int* __restrict__ cpd,
                           const int* __restrict__ pcs, const int* __restrict__ pcd,
                           float* dcs, float* dcd, float* dps, float* dpd, int E) {
    int e = blockIdx.x * blockDim.x + threadIdx.x;
    if (e >= E) return;
    atomicAdd(dcs + cps[e], 1.0f);
    atomicAdd(dcd + cpd[e], 1.0f);
    atomicAdd(dps + pcs[e], 1.0f);
    atomicAdd(dpd + pcd[e], 1.0f);
}

// ---------------- deg -> deg^-1/2 (in place) ----------------
__global__ void inv_kernel(float* deg, int n) {
    int i = blockIdx.x * blockDim.x + threadIdx.x;
    if (i >= n) return;
    float d = deg[i];
    deg[i] = (d > 0.0f) ? (1.0f / sqrtf(d)) : 0.0f;
}

// ---------------- per-edge weights for both relations ----------------
__global__ void weight_kernel(const int* __restrict__ cps, const int* __restrict__ cpd,
                              const int* __restrict__ pcs, const int* __restrict__ pcd,
                              const float* __restrict__ ics, const float* __restrict__ icd,
                              const float* __restrict__ ips, const float* __restrict__ ipd,
                              float* w_cp, float* w_pc, int E) {
    int e = blockIdx.x * blockDim.x + threadIdx.x;
    if (e >= E) return;
    w_cp[e] = ics[cps[e]] * icd[cpd[e]];
    w_pc[e] = ips[pcs[e]] * ipd[pcd[e]];
}

// ---------------- fp32 GEMM: out = X[M,256] @ W[256,128] + b ----------------
// Block: 256 threads, tile 64 rows x 128 cols. Full K staged in LDS (64KB).
// Thread: 8 rows x 4 cols register blocking. Writes result to TWO buffers
// (ws h-buffer and d_out acc seed).
__launch_bounds__(256, 2)
__global__ void gemm_kernel(const float* __restrict__ X, const float* __restrict__ W,
                            const float* __restrict__ bias, float* __restrict__ out0,
                            float* __restrict__ out1, int M) {
    __shared__ float4 xs[64 * 64];   // 64 rows x 256 floats = 64 KiB
    const int t = threadIdx.x;
    const int rbase = blockIdx.x * 64;
    const float4* X4 = (const float4*)X;

    #pragma unroll
    for (int i = 0; i < 16; ++i) {
        int q = t + i * 256;
        int row = q >> 6;          // 64 float4 per row
        int c4  = q & 63;
        int g = rbase + row;
        xs[q] = (g < M) ? X4[(size_t)g * 64 + c4] : make_float4(0.f, 0.f, 0.f, 0.f);
    }
    __syncthreads();

    const int c4 = t & 31;         // float4-column index (cols c4*4 .. +3)
    const int r0 = (t >> 5) * 8;   // first of this thread's 8 rows
    const float4 bv = ((const float4*)bias)[c4];
    float4 acc[8];
    #pragma unroll
    for (int r = 0; r < 8; ++r) acc[r] = bv;

    const float4* W4 = (const float4*)W;   // W[k][c] at W4[k*32 + c4]

    for (int k4 = 0; k4 < 64; ++k4) {
        float4 xr[8];
        #pragma unroll
        for (int r = 0; r < 8; ++r) xr[r] = xs[(r0 + r) * 64 + k4];  // LDS broadcast
        const int k = k4 * 4;
        float4 w0 = W4[(k + 0) * 32 + c4];
        float4 w1 = W4[(k + 1) * 32 + c4];
        float4 w2 = W4[(k + 2) * 32 + c4];
        float4 w3 = W4[(k + 3) * 32 + c4];
        #pragma unroll
        for (int r = 0; r < 8; ++r) {
            acc[r].x += xr[r].x * w0.x + xr[r].y * w1.x + xr[r].z * w2.x + xr[r].w * w3.x;
            acc[r].y += xr[r].x * w0.y + xr[r].y * w1.y + xr[r].z * w2.y + xr[r].w * w3.y;
            acc[r].z += xr[r].x * w0.z + xr[r].y * w1.z + xr[r].z * w2.z + xr[r].w * w3.z;
            acc[r].w += xr[r].x * w0.w + xr[r].y * w1.w + xr[r].z * w2.w + xr[r].w * w3.w;
        }
    }

    #pragma unroll
    for (int r = 0; r < 8; ++r) {
        int g = rbase + r0 + r;
        if (g < M) {
            ((float4*)out0)[(size_t)g * 32 + c4] = acc[r];
            ((float4*)out1)[(size_t)g * 32 + c4] = acc[r];
        }
    }
}

// ---------------- edge aggregation: hdst[dst] += hsrc[src] * w ----------------
// 32 lanes per edge; each lane gathers one float4 (coalesced 512B row) and
// does 4 global f32 atomicAdds to the destination row.
__global__ void agg_kernel(const int* __restrict__ src, const int* __restrict__ dst,
                           const float* __restrict__ w, const float* __restrict__ hsrc,
                           float* __restrict__ hdst, int E) {
    int idx = blockIdx.x * blockDim.x + threadIdx.x;
    int e = idx >> 5;
    if (e >= E) return;
    int lane = idx & 31;
    int s = src[e];
    int d = dst[e];
    float we = w[e];
    float4 v = ((const float4*)hsrc)[(size_t)s * 32 + lane];
    float* o = hdst + (size_t)d * HD + (size_t)lane * 4;
    atomicAdd(o + 0, v.x * we);
    atomicAdd(o + 1, v.y * we);
    atomicAdd(o + 2, v.z * we);
    atomicAdd(o + 3, v.w * we);
}

// ---------------- final: acc = (h0 + l1 + l2)/3, L2-normalize rows ----------------
// One 64-lane wave per row (2 floats/lane); accOut holds h0 and receives result.
__global__ void norm_kernel(float* __restrict__ accOut, const float* __restrict__ b1,
                            const float* __restrict__ b2, int M) {
    int row = blockIdx.x * 4 + (threadIdx.x >> 6);
    if (row >= M) return;
    int lane = threadIdx.x & 63;
    size_t base = (size_t)row * HD + (size_t)lane * 2;
    float2 a  = *(const float2*)(accOut + base);
    float2 x1 = *(const float2*)(b1 + base);
    float2 x2 = *(const float2*)(b2 + base);
    const float s = 1.0f / 3.0f;
    float vx = (a.x + x1.x + x2.x) * s;
    float vy = (a.y + x1.y + x2.y) * s;
    float ss = vx * vx + vy * vy;
    #pragma unroll
    for (int off = 32; off > 0; off >>= 1) ss += __shfl_xor(ss, off);
    float inv = 1.0f / fmaxf(sqrtf(ss), 1e-12f);
    float2 r = make_float2(vx * inv, vy * inv);
    *(float2*)(accOut + base) = r;
}

extern "C" void kernel_launch(void* const* d_in, const int* in_sizes, int n_in,
                              void* d_out, int out_size, void* d_ws, size_t ws_size,
                              hipStream_t stream) {
    const float* x_p = (const float*)d_in[0];
    const float* x_c = (const float*)d_in[1];
    const float* W_p = (const float*)d_in[2];
    const float* b_p = (const float*)d_in[3];
    const float* W_c = (const float*)d_in[4];
    const float* b_c = (const float*)d_in[5];
    const int* pcs = (const int*)d_in[6];
    const int* pcd = (const int*)d_in[7];
    const int* cps = (const int*)d_in[8];
    const int* cpd = (const int*)d_in[9];

    const int Np = in_sizes[0] / KD;
    const int Nc = in_sizes[1] / KD;
    const int E  = in_sizes[6];

    // ---- workspace layout (all f32) ----
    float* ws    = (float*)d_ws;
    float* w_cp  = ws;                       // [E]
    float* w_pc  = w_cp + E;                 // [E]
    float* deg   = w_pc + E;                 // 2*(Np+Nc)
    float* dcs   = deg;                      // cp: src deg (company)   [Nc]
    float* dcd   = dcs + Nc;                 // cp: dst deg (project)   [Np]
    float* dps   = dcd + Np;                 // pc: src deg (project)   [Np]
    float* dpd   = dps + Np;                 // pc: dst deg (company)   [Nc]
    float* bufP0 = deg + 2 * (size_t)(Np + Nc);     // [Np*HD]
    float* bufP1 = bufP0 + (size_t)Np * HD;         // [Np*HD]
    float* bufC0 = bufP1 + (size_t)Np * HD;         // [Nc*HD]
    float* bufC1 = bufC0 + (size_t)Nc * HD;         // [Nc*HD]

    float* outP = (float*)d_out;                    // acc_p lives here
    float* outC = outP + (size_t)Np * HD;           // acc_c lives here

    // ---- zero what we accumulate into ----
    hipMemsetAsync(deg,   0, 2 * (size_t)(Np + Nc) * sizeof(float), stream);
    hipMemsetAsync(bufP1, 0, (size_t)Np * HD * sizeof(float), stream);
    hipMemsetAsync(bufC1, 0, (size_t)Nc * HD * sizeof(float), stream);

    // ---- degrees -> inv-sqrt -> per-edge weights ----
    deg_kernel<<<(E + 255) / 256, 256, 0, stream>>>(cps, cpd, pcs, pcd, dcs, dcd, dps, dpd, E);
    int ndeg = 2 * (Np + Nc);
    inv_kernel<<<(ndeg + 255) / 256, 256, 0, stream>>>(deg, ndeg);
    weight_kernel<<<(E + 255) / 256, 256, 0, stream>>>(cps, cpd, pcs, pcd,
                                                       dcs, dcd, dps, dpd, w_cp, w_pc, E);

    // ---- h0 = X @ W + b  (written to ws buffer AND d_out acc seed) ----
    gemm_kernel<<<(Np + 63) / 64, 256, 0, stream>>>(x_p, W_p, b_p, bufP0, outP, Np);
    gemm_kernel<<<(Nc + 63) / 64, 256, 0, stream>>>(x_c, W_c, b_c, bufC0, outC, Nc);

    const long agg_threads = (long)E * 32;
    const int agg_blocks = (int)((agg_threads + 255) / 256);

    // ---- layer 1: new_p1 = Agg_cp(h_c0) -> bufP1 ; new_c1 = Agg_pc(h_p0) -> bufC1 ----
    agg_kernel<<<agg_blocks, 256, 0, stream>>>(cps, cpd, w_cp, bufC0, bufP1, E);
    agg_kernel<<<agg_blocks, 256, 0, stream>>>(pcs, pcd, w_pc, bufP0, bufC1, E);

    // re-zero layer-0 buffers for layer-2 outputs
    hipMemsetAsync(bufP0, 0, (size_t)Np * HD * sizeof(float), stream);
    hipMemsetAsync(bufC0, 0, (size_t)Nc * HD * sizeof(float), stream);

    // ---- layer 2: new_p2 = Agg_cp(new_c1) -> bufP0 ; new_c2 = Agg_pc(new_p1) -> bufC0 ----
    agg_kernel<<<agg_blocks, 256, 0, stream>>>(cps, cpd, w_cp, bufC1, bufP0, E);
    agg_kernel<<<agg_blocks, 256, 0, stream>>>(pcs, pcd, w_pc, bufP1, bufC0, E);

    // ---- acc = (h0 + l1 + l2)/3, row L2-normalize, in place in d_out ----
    norm_kernel<<<(Np + 3) / 4, 256, 0, stream>>>(outP, bufP1, bufP0, Np);
    norm_kernel<<<(Nc + 3) / 4, 256, 0, stream>>>(outC, bufC1, bufC0, Nc);
}

// Round 2
// 1024.688 us; speedup vs baseline: 7.0384x; 7.0384x over previous
//
#include <hip/hip_runtime.h>
#include <math.h>

#define HD 128   // HIDDEN_DIM
#define KD 256   // INPUT_DIM

// ---------------- degree count (int), per relation src & dst ----------------
__global__ void deg_kernel(const int* __restrict__ cps, const int* __restrict__ cpd,
                           const int* __restrict__ pcs, const int* __restrict__ pcd,
                           int* c_cps, int* c_pcs, int* c_cpd, int* c_pcd, int E) {
    int e = blockIdx.x * blockDim.x + threadIdx.x;
    if (e >= E) return;
    atomicAdd(c_cps + cps[e], 1);
    atomicAdd(c_pcs + pcs[e], 1);
    atomicAdd(c_cpd + cpd[e], 1);
    atomicAdd(c_pcd + pcd[e], 1);
}

// ---------------- exclusive scan, 3-phase (1024 elems / block) ----------------
__global__ void scanA(int* data, int* bsums, int n) {
    __shared__ int tmp[256];
    const int t = threadIdx.x;
    const int base = blockIdx.x * 1024 + t * 4;
    int v[4], s = 0;
    #pragma unroll
    for (int i = 0; i < 4; ++i) { v[i] = (base + i < n) ? data[base + i] : 0; s += v[i]; }
    tmp[t] = s;
    __syncthreads();
    for (int off = 1; off < 256; off <<= 1) {
        int x = (t >= off) ? tmp[t - off] : 0;
        __syncthreads();
        tmp[t] += x;
        __syncthreads();
    }
    int ex = tmp[t] - s;   // exclusive prefix within block
    #pragma unroll
    for (int i = 0; i < 4; ++i) { if (base + i < n) data[base + i] = ex; ex += v[i]; }
    if (t == 255) bsums[blockIdx.x] = tmp[255];
}

__global__ void scanB(int* bs, int nb) {   // nb <= 256
    __shared__ int tmp[256];
    const int t = threadIdx.x;
    int v = (t < nb) ? bs[t] : 0;
    tmp[t] = v;
    __syncthreads();
    for (int off = 1; off < 256; off <<= 1) {
        int x = (t >= off) ? tmp[t - off] : 0;
        __syncthreads();
        tmp[t] += x;
        __syncthreads();
    }
    if (t < nb) bs[t] = tmp[t] - v;
}

__global__ void scanC(int* data, const int* __restrict__ bsums, int n) {
    const int t = threadIdx.x;
    const int base = blockIdx.x * 1024 + t * 4;
    const int add = bsums[blockIdx.x];
    #pragma unroll
    for (int i = 0; i < 4; ++i) if (base + i < n) data[base + i] += add;
}

// ---------------- int degree -> f32 deg^-1/2, in place ----------------
__global__ void inv_inplace(int* cnt, int n) {
    int i = blockIdx.x * blockDim.x + threadIdx.x;
    if (i >= n) return;
    int d = cnt[i];
    float f = (d > 0) ? (1.0f / sqrtf((float)d)) : 0.0f;
    ((float*)cnt)[i] = f;
}

// ---------------- counting-sort scatter: build dst-sorted src lists ----------------
// off arrays hold exclusive scan; atomicAdd cursor advances them to END offsets.
__global__ void scatter_kernel(const int* __restrict__ cps, const int* __restrict__ cpd,
                               const int* __restrict__ pcs, const int* __restrict__ pcd,
                               int* off_cp, int* off_pc, int* scp, int* spc, int E) {
    int e = blockIdx.x * blockDim.x + threadIdx.x;
    if (e >= E) return;
    int p1 = atomicAdd(off_cp + cpd[e], 1);
    scp[p1] = cps[e];
    int p2 = atomicAdd(off_pc + pcd[e], 1);
    spc[p2] = pcs[e];
}

// ---------------- fp32 GEMM: out = X[M,256] @ W[256,128] + b ----------------
__launch_bounds__(256, 2)
__global__ void gemm_kernel(const float* __restrict__ X, const float* __restrict__ W,
                            const float* __restrict__ bias, float* __restrict__ out0,
                            float* __restrict__ out1, int M) {
    __shared__ float4 xs[64 * 64];   // 64 rows x 256 floats = 64 KiB
    const int t = threadIdx.x;
    const int rbase = blockIdx.x * 64;
    const float4* X4 = (const float4*)X;

    #pragma unroll
    for (int i = 0; i < 16; ++i) {
        int q = t + i * 256;
        int row = q >> 6;
        int c4  = q & 63;
        int g = rbase + row;
        xs[q] = (g < M) ? X4[(size_t)g * 64 + c4] : make_float4(0.f, 0.f, 0.f, 0.f);
    }
    __syncthreads();

    const int c4 = t & 31;
    const int r0 = (t >> 5) * 8;
    const float4 bv = ((const float4*)bias)[c4];
    float4 acc[8];
    #pragma unroll
    for (int r = 0; r < 8; ++r) acc[r] = bv;

    const float4* W4 = (const float4*)W;

    for (int k4 = 0; k4 < 64; ++k4) {
        float4 xr[8];
        #pragma unroll
        for (int r = 0; r < 8; ++r) xr[r] = xs[(r0 + r) * 64 + k4];
        const int k = k4 * 4;
        float4 w0 = W4[(k + 0) * 32 + c4];
        float4 w1 = W4[(k + 1) * 32 + c4];
        float4 w2 = W4[(k + 2) * 32 + c4];
        float4 w3 = W4[(k + 3) * 32 + c4];
        #pragma unroll
        for (int r = 0; r < 8; ++r) {
            acc[r].x += xr[r].x * w0.x + xr[r].y * w1.x + xr[r].z * w2.x + xr[r].w * w3.x;
            acc[r].y += xr[r].x * w0.y + xr[r].y * w1.y + xr[r].z * w2.y + xr[r].w * w3.y;
            acc[r].z += xr[r].x * w0.z + xr[r].y * w1.z + xr[r].z * w2.z + xr[r].w * w3.z;
            acc[r].w += xr[r].x * w0.w + xr[r].y * w1.w + xr[r].z * w2.w + xr[r].w * w3.w;
        }
    }

    #pragma unroll
    for (int r = 0; r < 8; ++r) {
        int g = rbase + r0 + r;
        if (g < M) {
            ((float4*)out0)[(size_t)g * 32 + c4] = acc[r];
            ((float4*)out1)[(size_t)g * 32 + c4] = acc[r];
        }
    }
}

// ---------------- CSR aggregation: one 64-lane wave per dst row ----------------
// off holds END offsets (post-scatter); beg = off[row-1]. Each lane owns 2 of
// the 128 output floats; edges broadcast via shfl; no atomics.
__global__ void agg_csr(const int* __restrict__ off, const int* __restrict__ ssrc,
                        const float* __restrict__ invs, const float* __restrict__ hsrc,
                        float* __restrict__ hdst, int M) {
    int row = blockIdx.x * 4 + (threadIdx.x >> 6);
    if (row >= M) return;
    const int lane = threadIdx.x & 63;
    const int end = off[row];
    const int beg = (row > 0) ? off[row - 1] : 0;
    float2 acc = make_float2(0.f, 0.f);
    const int deg = end - beg;
    if (deg > 0) {
        const float id = 1.0f / sqrtf((float)deg);
        for (int base = beg; base < end; base += 64) {
            int n = end - base;
            if (n > 64) n = 64;
            int sl = 0; float wl = 0.f;
            if (lane < n) {
                sl = ssrc[base + lane];
                wl = invs[sl];
            }
            for (int j = 0; j < n; ++j) {
                int s = __shfl(sl, j);
                float wt = __shfl(wl, j) * id;
                const float2 v = *(const float2*)(hsrc + (size_t)s * HD + lane * 2);
                acc.x = fmaf(v.x, wt, acc.x);
                acc.y = fmaf(v.y, wt, acc.y);
            }
        }
    }
    *(float2*)(hdst + (size_t)row * HD + lane * 2) = acc;
}

// ---------------- final: acc = (h0 + l1 + l2)/3, L2-normalize rows ----------------
__global__ void norm_kernel(float* __restrict__ accOut, const float* __restrict__ b1,
                            const float* __restrict__ b2, int M) {
    int row = blockIdx.x * 4 + (threadIdx.x >> 6);
    if (row >= M) return;
    int lane = threadIdx.x & 63;
    size_t base = (size_t)row * HD + (size_t)lane * 2;
    float2 a  = *(const float2*)(accOut + base);
    float2 x1 = *(const float2*)(b1 + base);
    float2 x2 = *(const float2*)(b2 + base);
    const float s = 1.0f / 3.0f;
    float vx = (a.x + x1.x + x2.x) * s;
    float vy = (a.y + x1.y + x2.y) * s;
    float ss = vx * vx + vy * vy;
    #pragma unroll
    for (int off = 32; off > 0; off >>= 1) ss += __shfl_xor(ss, off);
    float inv = 1.0f / fmaxf(sqrtf(ss), 1e-12f);
    float2 r = make_float2(vx * inv, vy * inv);
    *(float2*)(accOut + base) = r;
}

extern "C" void kernel_launch(void* const* d_in, const int* in_sizes, int n_in,
                              void* d_out, int out_size, void* d_ws, size_t ws_size,
                              hipStream_t stream) {
    const float* x_p = (const float*)d_in[0];
    const float* x_c = (const float*)d_in[1];
    const float* W_p = (const float*)d_in[2];
    const float* b_p = (const float*)d_in[3];
    const float* W_c = (const float*)d_in[4];
    const float* b_c = (const float*)d_in[5];
    const int* pcs = (const int*)d_in[6];
    const int* pcd = (const int*)d_in[7];
    const int* cps = (const int*)d_in[8];
    const int* cpd = (const int*)d_in[9];

    const int Np = in_sizes[0] / KD;
    const int Nc = in_sizes[1] / KD;
    const int E  = in_sizes[6];

    // ---- workspace layout (4B words), same 162.8 MB footprint as round 0 ----
    int* scp = (int*)d_ws;                 // [E]  cp edges sorted by project dst -> company src
    int* spc = scp + E;                    // [E]  pc edges sorted by company dst -> project src
    int* cnt = spc + E;                    // [c_cps Nc][c_pcs Np][c_cpd Np][c_pcd Nc]
    int* c_cps = cnt;                      // -> becomes f32 inv (company src deg, cp)
    int* c_pcs = c_cps + Nc;               // -> becomes f32 inv (project src deg, pc)
    int* c_cpd = c_pcs + Np;               // -> becomes off_cp (scan, then END offsets)
    int* c_pcd = c_cpd + Np;               // -> becomes off_pc
    float* bufP0 = (float*)(c_pcd + Nc);   // [Np*HD]
    float* bufP1 = bufP0 + (size_t)Np * HD;
    float* bufC0 = bufP1 + (size_t)Np * HD;
    float* bufC1 = bufC0 + (size_t)Nc * HD;

    float* outP = (float*)d_out;
    float* outC = outP + (size_t)Np * HD;

    // scan block-sum scratch lives at the head of d_out; GEMM overwrites it later
    int* bsumA = (int*)d_out;        // up to 128
    int* bsumB = bsumA + 128;        // up to 128

    const int ndegall = 2 * (Np + Nc);
    const int ndegsrc = Nc + Np;
    const int nblkP = (Np + 1023) / 1024;
    const int nblkC = (Nc + 1023) / 1024;

    hipMemsetAsync(cnt, 0, (size_t)ndegall * sizeof(int), stream);

    // ---- degrees ----
    deg_kernel<<<(E + 255) / 256, 256, 0, stream>>>(cps, cpd, pcs, pcd,
                                                    c_cps, c_pcs, c_cpd, c_pcd, E);
    // ---- exclusive scans of dst degrees (in place) ----
    scanA<<<nblkP, 256, 0, stream>>>(c_cpd, bsumA, Np);
    scanA<<<nblkC, 256, 0, stream>>>(c_pcd, bsumB, Nc);
    scanB<<<1, 256, 0, stream>>>(bsumA, nblkP);
    scanB<<<1, 256, 0, stream>>>(bsumB, nblkC);
    scanC<<<nblkP, 256, 0, stream>>>(c_cpd, bsumA, Np);
    scanC<<<nblkC, 256, 0, stream>>>(c_pcd, bsumB, Nc);

    // ---- src-degree -> inv-sqrt (in place, int->float) ----
    inv_inplace<<<(ndegsrc + 255) / 256, 256, 0, stream>>>(cnt, ndegsrc);

    // ---- counting-sort scatter (off arrays advance to END offsets) ----
    scatter_kernel<<<(E + 255) / 256, 256, 0, stream>>>(cps, cpd, pcs, pcd,
                                                        c_cpd, c_pcd, scp, spc, E);

    // ---- h0 = X @ W + b  (ws buffer AND d_out acc seed) ----
    gemm_kernel<<<(Np + 63) / 64, 256, 0, stream>>>(x_p, W_p, b_p, bufP0, outP, Np);
    gemm_kernel<<<(Nc + 63) / 64, 256, 0, stream>>>(x_c, W_c, b_c, bufC0, outC, Nc);

    const float* i_cps = (const float*)c_cps;   // inv company out-deg (cp)
    const float* i_pcs = (const float*)c_pcs;   // inv project out-deg (pc)

    // ---- layer 1 ----
    agg_csr<<<(Np + 3) / 4, 256, 0, stream>>>(c_cpd, scp, i_cps, bufC0, bufP1, Np);
    agg_csr<<<(Nc + 3) / 4, 256, 0, stream>>>(c_pcd, spc, i_pcs, bufP0, bufC1, Nc);
    // ---- layer 2 (overwrites consumed layer-0 buffers) ----
    agg_csr<<<(Np + 3) / 4, 256, 0, stream>>>(c_cpd, scp, i_cps, bufC1, bufP0, Np);
    agg_csr<<<(Nc + 3) / 4, 256, 0, stream>>>(c_pcd, spc, i_pcs, bufP1, bufC0, Nc);

    // ---- acc = (h0 + l1 + l2)/3, row L2-normalize, in place in d_out ----
    norm_kernel<<<(Np + 3) / 4, 256, 0, stream>>>(outP, bufP1, bufP0, Np);
    norm_kernel<<<(Nc + 3) / 4, 256, 0, stream>>>(outC, bufC1, bufC0, Nc);
}